// Round 1
// baseline (556.406 us; speedup 1.0000x reference)
//
#include <hip/hip_runtime.h>

#define B_SZ 256
#define S_LEN 512
#define NT 128
#define PAD 127
#define LN2F 0.69314718055994530942f
#define RENORM 0x1p-62f

typedef float v2f __attribute__((ext_vector_type(2)));
typedef float v4f __attribute__((ext_vector_type(4)));

// Barrier draining only LDS (lgkmcnt), NOT vmcnt — emission prefetch loads
// stay in flight across steps.
__device__ __forceinline__ void lds_barrier() {
    asm volatile("s_waitcnt lgkmcnt(0)\n\ts_barrier" ::: "memory");
}

// One block per batch; 4 waves split K. Wave w holds exp(trans[k][:]) for
// k in [32w,32w+32) (64 VGPRs). Alpha lives in LDS (4 rotating buffers):
//   step t: uniform-broadcast ds_read_b128 of slice from aL[(t-1)&3],
//           32 pk-FMAs, fold exp(em), ds_add_f32 into aL[t&3] (pre-zeroed),
//           zero aL[(t+1)&3], ONE lds_barrier.
// This replaces 32 readlane broadcasts + replicated 4-way reduction+select
// (~40 VALU/step) with 8 broadcast LDS reads + 2 LDS atomics.
__global__ __launch_bounds__(256, 1) void crf_fused(
    const float* __restrict__ em,      // (B,S,T)
    const int*   __restrict__ tags,    // (B,S)
    const float* __restrict__ startT,  // (T)
    const float* __restrict__ endT,    // (T)
    const float* __restrict__ trans,   // (T,T)
    float* __restrict__ out)
{
    const int b   = blockIdx.x;
    const int tid = threadIdx.x;
    const int w   = tid >> 6;          // wave 0..3
    const int l   = tid & 63;          // lane

    __shared__ __align__(16) float aL[4][NT];   // rotating alpha buffers
    __shared__ float maskv[S_LEN + 1];          // per-step mask (padded)
    __shared__ float nred[4];
    __shared__ int   cred[4];

    const float* em_b = em + (size_t)b * S_LEN * NT;
    const int*   tg_b = tags + (size_t)b * S_LEN;

    // ---- stage per-step masks ----
    for (int q = tid; q < S_LEN; q += 256)
        maskv[q] = (tg_b[q] != PAD) ? 1.0f : 0.0f;
    if (tid == 0) maskv[S_LEN] = 1.0f;

    // ---- numerator partial + valid count (wave w covers chunks 2w, 2w+1) ----
    float numSum = 0.f;
    int   cnt    = 0;
    #pragma unroll
    for (int q = 0; q < 2; ++q) {
        int t  = 64 * (2 * w + q) + l;
        int tv = tg_b[t];
        cnt += (tv != PAD) ? 1 : 0;
        float emg = em_b[(size_t)t * NT + tv];
        if (t == 0) {
            numSum += startT[tv] + emg;
        } else {
            int tp = tg_b[t - 1];
            float v = trans[tp * NT + tv] + emg;
            numSum += (tv != PAD) ? v : 0.f;
        }
    }
    #pragma unroll
    for (int off = 32; off > 0; off >>= 1) {
        numSum += __shfl_down(numSum, off, 64);
        cnt    += __shfl_down(cnt, off, 64);
    }
    if (l == 0) { nred[w] = numSum; cred[w] = cnt; }

    // ---- column registers for this wave's K-slice ----
    const int k0 = 32 * w;
    v2f col[32];
    #pragma unroll
    for (int i = 0; i < 32; ++i) {
        col[i].x = __expf(trans[(k0 + i) * NT + l]);
        col[i].y = __expf(trans[(k0 + i) * NT + 64 + l]);
    }

    // ---- alpha init (t=0) into aL[0]; pre-zero aL[1] (acc for t=1) ----
    if (w == 0) {
        aL[0][l]      = __expf(startT[l]      + em_b[l]);
        aL[0][64 + l] = __expf(startT[64 + l] + em_b[64 + l]);
    }
    if (tid < 128) aL[1][tid] = 0.0f;

    // ---- named-register emission pipeline: slot s holds em for t = s+1 (mod 8) ----
    float rA0 = em_b[1 * NT + l], rB0 = em_b[1 * NT + 64 + l];
    float rA1 = em_b[2 * NT + l], rB1 = em_b[2 * NT + 64 + l];
    float rA2 = em_b[3 * NT + l], rB2 = em_b[3 * NT + 64 + l];
    float rA3 = em_b[4 * NT + l], rB3 = em_b[4 * NT + 64 + l];
    float rA4 = em_b[5 * NT + l], rB4 = em_b[5 * NT + 64 + l];
    float rA5 = em_b[6 * NT + l], rB5 = em_b[6 * NT + 64 + l];
    float rA6 = em_b[7 * NT + l], rB6 = em_b[7 * NT + 64 + l];
    float rA7 = em_b[8 * NT + l], rB7 = em_b[8 * NT + 64 + l];

    __syncthreads();   // maskv + nred + aL[0]/aL[1] visible

    float mvCur = maskv[1];   // mask for the first step (prefetched)

#define FMA4(Q, I0)                                \
    a0_ += (v2f){Q.x, Q.x} * col[(I0) + 0];        \
    a1_ += (v2f){Q.y, Q.y} * col[(I0) + 1];        \
    a2_ += (v2f){Q.z, Q.z} * col[(I0) + 2];        \
    a3_ += (v2f){Q.w, Q.w} * col[(I0) + 3];

#define STEP(SL, T, RN)                                                      \
  {                                                                          \
    const int t_ = (T);                                                      \
    const float* srcp_ = &aL[(t_ - 1) & 3][32 * w];                          \
    v4f q0_ = ((const v4f*)srcp_)[0];   /* uniform addr -> broadcast */      \
    v4f q1_ = ((const v4f*)srcp_)[1];                                        \
    v4f q2_ = ((const v4f*)srcp_)[2];                                        \
    v4f q3_ = ((const v4f*)srcp_)[3];                                        \
    v4f q4_ = ((const v4f*)srcp_)[4];                                        \
    v4f q5_ = ((const v4f*)srcp_)[5];                                        \
    v4f q6_ = ((const v4f*)srcp_)[6];                                        \
    v4f q7_ = ((const v4f*)srcp_)[7];                                        \
    int tn_ = (t_ + 8 < S_LEN) ? t_ + 8 : S_LEN - 1;                         \
    float nA_ = em_b[(size_t)tn_ * NT + l];                                  \
    float nB_ = em_b[(size_t)tn_ * NT + 64 + l];                             \
    float mv_ = mvCur;                                                       \
    mvCur = maskv[t_ + 1];             /* prefetch next step's mask */       \
    float e0_ = __expf(rA##SL);                                              \
    float e1_ = __expf(rB##SL);                                              \
    rA##SL = nA_; rB##SL = nB_;                                              \
    if (tid < 128) aL[(t_ + 1) & 3][tid] = 0.0f;  /* safe: read 2 steps ago */\
    if (mv_ != 0.0f) {                 /* block-uniform branch */            \
      v2f a0_ = {0.f,0.f}, a1_ = {0.f,0.f}, a2_ = {0.f,0.f}, a3_ = {0.f,0.f};\
      FMA4(q0_, 0)  FMA4(q1_, 4)  FMA4(q2_, 8)  FMA4(q3_, 12)                \
      FMA4(q4_, 16) FMA4(q5_, 20) FMA4(q6_, 24) FMA4(q7_, 28)                \
      v2f p_ = (a0_ + a1_) + (a2_ + a3_);                                    \
      p_.x *= e0_;  p_.y *= e1_;       /* fold exp(em) into partial */       \
      if (RN) { p_.x *= RENORM; p_.y *= RENORM; }                            \
      atomicAdd(&aL[t_ & 3][l],      p_.x);                                  \
      atomicAdd(&aL[t_ & 3][64 + l], p_.y);                                  \
    } else if (w == 0) {               /* masked step: carry alpha over */   \
      float cx_ = aL[(t_ - 1) & 3][l];                                       \
      float cy_ = aL[(t_ - 1) & 3][64 + l];                                  \
      if (RN) { cx_ *= RENORM; cy_ *= RENORM; }                              \
      aL[t_ & 3][l]      = cx_;                                              \
      aL[t_ & 3][64 + l] = cy_;                                              \
    }                                                                        \
    lds_barrier();                                                           \
  }

    // chunk 0: t = 1..7  (slot = (t-1)&7)
    STEP(0, 1, false) STEP(1, 2, false) STEP(2, 3, false) STEP(3, 4, false)
    STEP(4, 5, false) STEP(5, 6, false) STEP(6, 7, false)

    // chunks 1..63: t = 8c .. 8c+7 ; renorm at t = 8c (63 renorms total)
    for (int c = 1; c < 64; ++c) {
        const int t0 = c * 8;
        STEP(7, t0,     true)
        STEP(0, t0 + 1, false) STEP(1, t0 + 2, false) STEP(2, t0 + 3, false)
        STEP(3, t0 + 4, false) STEP(4, t0 + 5, false) STEP(5, t0 + 6, false)
        STEP(6, t0 + 7, false)
    }
#undef STEP
#undef FMA4

    // ---- finalize: wave 0 computes denominator and writes output ----
    // alpha_511 lives in aL[511 & 3] = aL[3]
    if (w == 0) {
        float ax = aL[3][l];
        float ay = aL[3][64 + l];
        float pe = ax * __expf(endT[l]) + ay * __expf(endT[64 + l]);
        #pragma unroll
        for (int off = 32; off > 0; off >>= 1)
            pe += __shfl_down(pe, off, 64);
        if (l == 0) {
            int   cT   = (cred[0] + cred[1]) + (cred[2] + cred[3]);
            int   last = tg_b[cT - 1];
            float num  = (nred[0] + nred[1]) + (nred[2] + nred[3]) + endT[last];
            float den  = 63.0f * 62.0f * LN2F + logf(pe);
            atomicAdd(out, (num - den) * (1.0f / (float)B_SZ));
        }
    }
}

extern "C" void kernel_launch(void* const* d_in, const int* in_sizes, int n_in,
                              void* d_out, int out_size, void* d_ws, size_t ws_size,
                              hipStream_t stream) {
    const float* em     = (const float*)d_in[0];
    const int*   tags   = (const int*)d_in[1];
    const float* startT = (const float*)d_in[2];
    const float* endT   = (const float*)d_in[3];
    const float* trans  = (const float*)d_in[4];
    float* out = (float*)d_out;

    hipMemsetAsync(out, 0, sizeof(float), stream);
    crf_fused<<<B_SZ, 256, 0, stream>>>(em, tags, startT, endT, trans, out);
}

// Round 2
// 369.142 us; speedup vs baseline: 1.5073x; 1.5073x over previous
//
#include <hip/hip_runtime.h>

#define B_SZ 256
#define S_LEN 512
#define NT 128
#define PAD 127
#define LN2F 0.69314718055994530942f
#define RENORM 0x1p-62f

typedef float v2f __attribute__((ext_vector_type(2)));

__device__ __forceinline__ float bcastf(float v, int k) {
    return __uint_as_float((unsigned)__builtin_amdgcn_readlane((int)__float_as_uint(v), k));
}

// Broadcast lane k of v into a 64-bit SGPR pair {s,s} (shift/or run on the
// free SALU pipe). Feeds v_pk_fma_f32 src0 directly.
__device__ __forceinline__ unsigned long long splat64(float v, int k) {
    unsigned sb = (unsigned)__builtin_amdgcn_readlane((int)__float_as_uint(v), k);
    return ((unsigned long long)sb << 32) | (unsigned long long)sb;
}

// acc = {s,s} * c + acc in ONE VALU instruction (VOP3P, SGPR-pair src0).
// Replaces readlane + 2x v_mov + 2x v_fmac (~10 cyc/k -> 4 cyc/k).
__device__ __forceinline__ void pkfma(v2f& acc, unsigned long long sp, v2f c) {
    asm("v_pk_fma_f32 %0, %1, %2, %0" : "+v"(acc) : "s"(sp), "v"(c));
}

// Barrier draining only LDS (lgkmcnt), NOT vmcnt — emission prefetch loads
// stay in flight across steps.
__device__ __forceinline__ void lds_barrier() {
    asm volatile("s_waitcnt lgkmcnt(0)\n\ts_barrier" ::: "memory");
}

// One block per batch; 4 waves split K. Wave w holds exp(trans[k][:]) for
// k in [32w,32w+32) (64 VGPRs). alpha replicated per wave (a.x=alpha[lane],
// a.y=alpha[lane+64]). Emissions: 16 NAMED register slots (8-step software
// pipeline). Partials exchanged as v2f pairs: 1 ds_write_b64 + 4 ds_read_b64.
__global__ __launch_bounds__(256, 1) void crf_fused(
    const float* __restrict__ em,      // (B,S,T)
    const int*   __restrict__ tags,    // (B,S)
    const float* __restrict__ startT,  // (T)
    const float* __restrict__ endT,    // (T)
    const float* __restrict__ trans,   // (T,T)
    float* __restrict__ out)
{
    const int b   = blockIdx.x;
    const int tid = threadIdx.x;
    const int w   = tid >> 6;          // wave 0..3
    const int l   = tid & 63;          // lane

    __shared__ __align__(16) v2f bufp[2][4][64];   // [parity][wave][lane] = {p[l], p[l+64]}
    __shared__ float maskv[S_LEN];     // per-step mask as float
    __shared__ float nred[4];
    __shared__ int   cred[4];

    const float* em_b = em + (size_t)b * S_LEN * NT;
    const int*   tg_b = tags + (size_t)b * S_LEN;

    // ---- stage per-step masks ----
    for (int q = tid; q < S_LEN; q += 256)
        maskv[q] = (tg_b[q] != PAD) ? 1.0f : 0.0f;

    // ---- numerator partial + valid count (wave w covers chunks 2w, 2w+1) ----
    float numSum = 0.f;
    int   cnt    = 0;
    #pragma unroll
    for (int q = 0; q < 2; ++q) {
        int t  = 64 * (2 * w + q) + l;
        int tv = tg_b[t];
        cnt += (tv != PAD) ? 1 : 0;
        float emg = em_b[(size_t)t * NT + tv];
        if (t == 0) {
            numSum += startT[tv] + emg;
        } else {
            int tp = tg_b[t - 1];
            float v = trans[tp * NT + tv] + emg;
            numSum += (tv != PAD) ? v : 0.f;
        }
    }
    #pragma unroll
    for (int off = 32; off > 0; off >>= 1) {
        numSum += __shfl_down(numSum, off, 64);
        cnt    += __shfl_down(cnt, off, 64);
    }
    if (l == 0) { nred[w] = numSum; cred[w] = cnt; }

    // ---- column registers for this wave's K-slice ----
    const int k0 = 32 * w;
    v2f col[32];
    #pragma unroll
    for (int i = 0; i < 32; ++i) {
        col[i].x = __expf(trans[(k0 + i) * NT + l]);
        col[i].y = __expf(trans[(k0 + i) * NT + 64 + l]);
    }

    // ---- alpha init (t=0), replicated on all waves ----
    v2f a;
    a.x = __expf(startT[l]      + em_b[l]);
    a.y = __expf(startT[64 + l] + em_b[64 + l]);

    const bool useX = (w < 2);
    const int  base = (w & 1) * 32;

    // ---- named-register emission pipeline: slot s holds em for t = s+1 (mod 8) ----
    float rA0 = em_b[1 * NT + l], rB0 = em_b[1 * NT + 64 + l];
    float rA1 = em_b[2 * NT + l], rB1 = em_b[2 * NT + 64 + l];
    float rA2 = em_b[3 * NT + l], rB2 = em_b[3 * NT + 64 + l];
    float rA3 = em_b[4 * NT + l], rB3 = em_b[4 * NT + 64 + l];
    float rA4 = em_b[5 * NT + l], rB4 = em_b[5 * NT + 64 + l];
    float rA5 = em_b[6 * NT + l], rB5 = em_b[6 * NT + 64 + l];
    float rA6 = em_b[7 * NT + l], rB6 = em_b[7 * NT + 64 + l];
    float rA7 = em_b[8 * NT + l], rB7 = em_b[8 * NT + 64 + l];

    __syncthreads();   // maskv + nred visible; one-time full barrier

#define STEP(SL, T, RN)                                                      \
  {                                                                          \
    const int t_   = (T);                                                    \
    const int par_ = t_ & 1;                                                 \
    int   tn_ = (t_ + 8 < S_LEN) ? t_ + 8 : S_LEN - 1;                       \
    float nA_ = em_b[(size_t)tn_ * NT + l];                                  \
    float nB_ = em_b[(size_t)tn_ * NT + 64 + l];                             \
    float mv_ = maskv[t_];                                                   \
    float e0_ = __expf(rA##SL);                                              \
    float e1_ = __expf(rB##SL);                                              \
    rA##SL = nA_; rB##SL = nB_;                                              \
    float sreg_ = useX ? a.x : a.y;                                          \
    v2f a0_ = {0.f,0.f}, a1_ = {0.f,0.f}, a2_ = {0.f,0.f}, a3_ = {0.f,0.f};  \
    _Pragma("unroll")                                                        \
    for (int i_ = 0; i_ < 32; i_ += 4) {                                     \
      pkfma(a0_, splat64(sreg_, base + i_),     col[i_]);                    \
      pkfma(a1_, splat64(sreg_, base + i_ + 1), col[i_ + 1]);                \
      pkfma(a2_, splat64(sreg_, base + i_ + 2), col[i_ + 2]);                \
      pkfma(a3_, splat64(sreg_, base + i_ + 3), col[i_ + 3]);                \
    }                                                                        \
    v2f p_ = (a0_ + a1_) + (a2_ + a3_);                                      \
    p_.x *= e0_;  p_.y *= e1_;          /* fold exp(em) into partial */      \
    bufp[par_][w][l] = p_;              /* one ds_write_b64 */               \
    lds_barrier();                                                           \
    v2f q0_ = bufp[par_][0][l], q1_ = bufp[par_][1][l];                      \
    v2f q2_ = bufp[par_][2][l], q3_ = bufp[par_][3][l];                      \
    v2f qs_ = (q0_ + q1_) + (q2_ + q3_);                                     \
    bool u_  = (mv_ != 0.0f);                                                \
    a.x = u_ ? qs_.x : a.x;                                                  \
    a.y = u_ ? qs_.y : a.y;                                                  \
    if (RN) { a.x *= RENORM; a.y *= RENORM; }                                \
  }

    // chunk 0: t = 1..7  (slot = (t-1)&7)
    STEP(0, 1, false) STEP(1, 2, false) STEP(2, 3, false) STEP(3, 4, false)
    STEP(4, 5, false) STEP(5, 6, false) STEP(6, 7, false)

    // chunks 1..63: t = 8c .. 8c+7 ; renorm at t = 8c (63 renorms total)
    for (int c = 1; c < 64; ++c) {
        const int t0 = c * 8;
        STEP(7, t0,     true)
        STEP(0, t0 + 1, false) STEP(1, t0 + 2, false) STEP(2, t0 + 3, false)
        STEP(3, t0 + 4, false) STEP(4, t0 + 5, false) STEP(5, t0 + 6, false)
        STEP(6, t0 + 7, false)
    }
#undef STEP

    // ---- finalize: wave 0 computes denominator and writes output ----
    if (w == 0) {
        float pe = a.x * __expf(endT[l]) + a.y * __expf(endT[64 + l]);
        #pragma unroll
        for (int off = 32; off > 0; off >>= 1)
            pe += __shfl_down(pe, off, 64);
        if (l == 0) {
            int   cT   = (cred[0] + cred[1]) + (cred[2] + cred[3]);
            int   last = tg_b[cT - 1];
            float num  = (nred[0] + nred[1]) + (nred[2] + nred[3]) + endT[last];
            float den  = 63.0f * 62.0f * LN2F + logf(pe);
            atomicAdd(out, (num - den) * (1.0f / (float)B_SZ));
        }
    }
}

extern "C" void kernel_launch(void* const* d_in, const int* in_sizes, int n_in,
                              void* d_out, int out_size, void* d_ws, size_t ws_size,
                              hipStream_t stream) {
    const float* em     = (const float*)d_in[0];
    const int*   tags   = (const int*)d_in[1];
    const float* startT = (const float*)d_in[2];
    const float* endT   = (const float*)d_in[3];
    const float* trans  = (const float*)d_in[4];
    float* out = (float*)d_out;

    hipMemsetAsync(out, 0, sizeof(float), stream);
    crf_fused<<<B_SZ, 256, 0, stream>>>(em, tags, startT, endT, trans, out);
}

// Round 3
// 294.018 us; speedup vs baseline: 1.8924x; 1.2555x over previous
//
#include <hip/hip_runtime.h>

#define B_SZ 256
#define S_LEN 512
#define NT 128
#define PAD 127
#define LN2F 0.69314718055994530942f
#define RENORM 0x1p-62f

typedef float v2f __attribute__((ext_vector_type(2)));
typedef float v4f __attribute__((ext_vector_type(4)));

// acc += ap * c, packed f32 pair, all VGPR operands (no SGPR, no op_sel).
__device__ __forceinline__ void pkfma(v2f& acc, v2f ap, v2f c) {
    asm("v_pk_fma_f32 %0, %1, %2, %0" : "+v"(acc) : "v"(ap), "v"(c));
}

// Barrier draining only LDS (lgkmcnt), NOT vmcnt — emission prefetch loads
// stay in flight across steps.
__device__ __forceinline__ void lds_barrier() {
    asm volatile("s_waitcnt lgkmcnt(0)\n\ts_barrier" ::: "memory");
}

// One block per batch; 4 waves split J (output states), NOT K.
//   wave w owns j in [32w, 32w+32); lane l owns j = 32w + (l>>1),
//   k-half kh = l&1 (k in [64*kh, 64*kh+64)).
// Per step: 16 broadcast ds_read_b128 of alpha (2 distinct addrs/wave),
// 32 v_pk_fma_f32 (k-pairs), shfl_xor(1) to merge k-halves, fold exp(em),
// write own alpha'[j] slice, ONE lds_barrier. No readlane, no splats,
// no cross-wave reduction.
__global__ __launch_bounds__(256, 1) void crf_fused(
    const float* __restrict__ em,      // (B,S,T)
    const int*   __restrict__ tags,    // (B,S)
    const float* __restrict__ startT,  // (T)
    const float* __restrict__ endT,    // (T)
    const float* __restrict__ trans,   // (T,T)
    float* __restrict__ out)
{
    const int b   = blockIdx.x;
    const int tid = threadIdx.x;
    const int w   = tid >> 6;          // wave 0..3
    const int l   = tid & 63;          // lane
    const int j   = 32 * w + (l >> 1); // this lane's output state
    const int kh  = l & 1;             // k-half: k in [64*kh, 64*kh+64)

    __shared__ __align__(16) float alphaL[2][NT];  // parity alpha buffers
    __shared__ float maskv[S_LEN];     // per-step mask as float
    __shared__ float nred[4];
    __shared__ int   cred[4];

    const float* em_b = em + (size_t)b * S_LEN * NT;
    const int*   tg_b = tags + (size_t)b * S_LEN;
    const float* emj  = em_b + j;      // per-lane emission column

    // ---- stage per-step masks ----
    for (int q = tid; q < S_LEN; q += 256)
        maskv[q] = (tg_b[q] != PAD) ? 1.0f : 0.0f;

    // ---- numerator partial + valid count (wave w covers chunks 2w, 2w+1) ----
    float numSum = 0.f;
    int   cnt    = 0;
    #pragma unroll
    for (int q = 0; q < 2; ++q) {
        int t  = 64 * (2 * w + q) + l;
        int tv = tg_b[t];
        cnt += (tv != PAD) ? 1 : 0;
        float emg = em_b[(size_t)t * NT + tv];
        if (t == 0) {
            numSum += startT[tv] + emg;
        } else {
            int tp = tg_b[t - 1];
            float v = trans[tp * NT + tv] + emg;
            numSum += (tv != PAD) ? v : 0.f;
        }
    }
    #pragma unroll
    for (int off = 32; off > 0; off >>= 1) {
        numSum += __shfl_down(numSum, off, 64);
        cnt    += __shfl_down(cnt, off, 64);
    }
    if (l == 0) { nred[w] = numSum; cred[w] = cnt; }

    // ---- column registers: col[m] = {expT[kb+2m][j], expT[kb+2m+1][j]} ----
    const int kb = 64 * kh;
    v2f col[32];
    #pragma unroll
    for (int m = 0; m < 32; ++m) {
        col[m].x = __expf(trans[(kb + 2 * m)     * NT + j]);
        col[m].y = __expf(trans[(kb + 2 * m + 1) * NT + j]);
    }

    // ---- alpha init (t=0): both lanes of a j-pair write same value ----
    float aOld = __expf(startT[j] + em_b[j]);
    alphaL[0][j] = aOld;

    // ---- named-register emission pipeline: slot s holds em[t=s+1 (mod 8)][j] ----
    float rE0 = emj[1 * NT], rE1 = emj[2 * NT], rE2 = emj[3 * NT], rE3 = emj[4 * NT];
    float rE4 = emj[5 * NT], rE5 = emj[6 * NT], rE6 = emj[7 * NT], rE7 = emj[8 * NT];

    __syncthreads();   // maskv + nred + alphaL[0] visible; one-time full barrier

#define STEP(SL, T, RN)                                                      \
  {                                                                          \
    const int t_ = (T);                                                      \
    const v4f* qb_ = (const v4f*)&alphaL[(t_ + 1) & 1][kb];                  \
    float mv_ = maskv[t_];                                                   \
    int   tn_ = (t_ + 8 < S_LEN) ? t_ + 8 : S_LEN - 1;                       \
    float nE_ = emj[(size_t)tn_ * NT];                                       \
    float e_  = __expf(rE##SL);                                              \
    rE##SL = nE_;                                                            \
    v2f ac0_ = {0.f,0.f}, ac1_ = {0.f,0.f}, ac2_ = {0.f,0.f}, ac3_ = {0.f,0.f};\
    _Pragma("unroll")                                                        \
    for (int i_ = 0; i_ < 16; i_ += 2) {                                     \
      v4f q0_ = qb_[i_], q1_ = qb_[i_ + 1];                                  \
      v2f l0_ = {q0_.x, q0_.y}, h0_ = {q0_.z, q0_.w};                        \
      v2f l1_ = {q1_.x, q1_.y}, h1_ = {q1_.z, q1_.w};                        \
      pkfma(ac0_, l0_, col[2 * i_]);                                         \
      pkfma(ac1_, h0_, col[2 * i_ + 1]);                                     \
      pkfma(ac2_, l1_, col[2 * i_ + 2]);                                     \
      pkfma(ac3_, h1_, col[2 * i_ + 3]);                                     \
    }                                                                        \
    v2f p_ = (ac0_ + ac1_) + (ac2_ + ac3_);                                  \
    float h_ = p_.x + p_.y;            /* this lane's k-half sum      */     \
    h_ += __shfl_xor(h_, 1, 64);       /* merge k-halves (quad-perm)  */     \
    float nw_  = h_ * e_;              /* fold exp(em)                */     \
    float sel_ = (mv_ != 0.0f) ? nw_ : aOld;                                 \
    if (RN) sel_ *= RENORM;                                                  \
    aOld = sel_;                                                             \
    alphaL[t_ & 1][j] = sel_;          /* both lanes write same value */     \
    lds_barrier();                                                           \
  }

    // chunk 0: t = 1..7  (slot = (t-1)&7)
    STEP(0, 1, false) STEP(1, 2, false) STEP(2, 3, false) STEP(3, 4, false)
    STEP(4, 5, false) STEP(5, 6, false) STEP(6, 7, false)

    // chunks 1..63: t = 8c .. 8c+7 ; renorm at t = 8c (63 renorms total)
    for (int c = 1; c < 64; ++c) {
        const int t0 = c * 8;
        STEP(7, t0,     true)
        STEP(0, t0 + 1, false) STEP(1, t0 + 2, false) STEP(2, t0 + 3, false)
        STEP(3, t0 + 4, false) STEP(4, t0 + 5, false) STEP(5, t0 + 6, false)
        STEP(6, t0 + 7, false)
    }
#undef STEP

    // ---- finalize: wave 0 computes denominator and writes output ----
    // alpha_511 lives in alphaL[511 & 1] = alphaL[1]; last STEP's barrier
    // makes it visible.
    if (w == 0) {
        float ax = alphaL[1][l];
        float ay = alphaL[1][64 + l];
        float pe = ax * __expf(endT[l]) + ay * __expf(endT[64 + l]);
        #pragma unroll
        for (int off = 32; off > 0; off >>= 1)
            pe += __shfl_down(pe, off, 64);
        if (l == 0) {
            int   cT   = (cred[0] + cred[1]) + (cred[2] + cred[3]);
            int   last = tg_b[cT - 1];
            float num  = (nred[0] + nred[1]) + (nred[2] + nred[3]) + endT[last];
            float den  = 63.0f * 62.0f * LN2F + logf(pe);
            atomicAdd(out, (num - den) * (1.0f / (float)B_SZ));
        }
    }
}

extern "C" void kernel_launch(void* const* d_in, const int* in_sizes, int n_in,
                              void* d_out, int out_size, void* d_ws, size_t ws_size,
                              hipStream_t stream) {
    const float* em     = (const float*)d_in[0];
    const int*   tags   = (const int*)d_in[1];
    const float* startT = (const float*)d_in[2];
    const float* endT   = (const float*)d_in[3];
    const float* trans  = (const float*)d_in[4];
    float* out = (float*)d_out;

    hipMemsetAsync(out, 0, sizeof(float), stream);
    crf_fused<<<B_SZ, 256, 0, stream>>>(em, tags, startT, endT, trans, out);
}